// Round 13
// baseline (443.294 us; speedup 1.0000x reference)
//
#include <hip/hip_runtime.h>

#define NB 4
#define CIN 64
#define COUT 64
#define H 128
#define W 128
#define H2 256
#define W2 256
#define HSX 23            // halo row stride (f32x2 units)
#define ZS 36             // zbuf row stride (ushorts) = 72B

// ws layout (float units)
#define WS_W    0         // bf16 weights ushort[32][64][32] = 32768 floats
#define WS_P1   32768     // per-tile partial sums  [4*64][256]
#define WS_P2   98304     // per-tile partial sumsq [4*64][256]
#define WS_MU   163840
#define WS_RSTD 164096

// ---------------------------------------------------------------------------
// Compile-time DISCO basis (replicates the numpy double-precision computation)
// ---------------------------------------------------------------------------
constexpr double csqrt(double x) {
    double g = x > 1.0 ? x : 1.0;
    for (int i = 0; i < 64; ++i) g = 0.5 * (g + x / g);
    return g;
}
constexpr double catan_pos(double x) {
    double f = 1.0;
    for (int i = 0; i < 6; ++i) { x = x / (1.0 + csqrt(1.0 + x * x)); f *= 2.0; }
    double x2 = x * x, s = 0.0, term = x;
    for (int n = 0; n < 10; ++n) { s += term / (2 * n + 1) * ((n & 1) ? -1.0 : 1.0); term *= x2; }
    return f * s;
}
constexpr double catan2c(double y, double x) {
    const double PI = 3.141592653589793;
    if (x == 0.0 && y == 0.0) return 0.0;
    double ax = x < 0 ? -x : x, ay = y < 0 ? -y : y;
    double a = (ax >= ay) ? catan_pos(ay / ax) : (PI / 2.0 - catan_pos(ax / ay));
    if (x < 0) a = PI - a;
    return (y < 0) ? -a : a;
}

struct PsiTab { double v[81][9]; };
constexpr PsiTab compute_psi() {
    PsiTab P{};
    const double hy = 1.0 / 256.0;
    const double rcut = 0.015;
    const double dr = 0.0075;
    const double PI = 3.141592653589793;
    const double TWO_PI = 6.283185307179586;
    const double dphi = PI / 2.0;
    for (int ky = 0; ky < 9; ++ky)
        for (int kx = 0; kx < 9; ++kx) {
            double dy = (double)(ky - 4) * hy;
            double dx = (double)(kx - 4) * hy;
            double r = csqrt(dy * dy + dx * dx);
            double phi = catan2c(dy, dx);
            if (phi < 0.0) phi += TWO_PI;
            for (int k = 0; k < 9; ++k) {
                int ir = (k == 0) ? 0 : ((k - 1) / 4 + 1);
                double ctr = ir * dr;
                double ad = r > ctr ? r - ctr : ctr - r;
                double rv = (ad <= dr && r <= rcut) ? 1.0 - ad / dr : 0.0;
                double val;
                if (k == 0) val = rv;
                else {
                    int ip = (k - 1) % 4;
                    double da = phi - ip * dphi; if (da < 0) da = -da;
                    double d2 = TWO_PI - da; if (d2 < da) da = d2;
                    double pv = (da <= dphi) ? 1.0 - da / dphi : 0.0;
                    val = rv * pv;
                }
                P.v[ky * 9 + kx][k] = val * (hy * hy);
            }
        }
    return P;
}

struct TapTab {
    int nt;
    int off[48];          // dy*HSX + dx (f32x2 offset from thread base)
    float val[48][9];
    bool nz[48][9];
};
constexpr TapTab make_taps() {
    TapTab T{};
    PsiTab P = compute_psi();
    for (int ky = 0; ky < 9; ++ky)
        for (int kx = 0; kx < 9; ++kx) {
            int t = ky * 9 + kx;
            bool any = false;
            for (int k = 0; k < 9; ++k) if (P.v[t][k] != 0.0) any = true;
            if (!any) continue;
            int dy = ky - 4, dx = kx - 4;    // support guarantees |dy|,|dx| <= 3
            T.off[T.nt] = dy * HSX + dx;
            for (int k = 0; k < 9; ++k) {
                T.val[T.nt][k] = (float)P.v[t][k];
                T.nz[T.nt][k] = (P.v[t][k] != 0.0);
            }
            T.nt++;
        }
    return T;
}
constexpr TapTab TT = make_taps();
constexpr int NT = TT.nt;
static_assert(NT > 0 && NT <= 48, "tap table overflow");

using f32x2  = __attribute__((ext_vector_type(2))) float;
using f32x4  = __attribute__((ext_vector_type(4))) float;
using bf16x8 = __attribute__((ext_vector_type(8))) short;

__device__ __forceinline__ unsigned short f2bf_rne(float f) {
    unsigned u = __float_as_uint(f);
    unsigned r = (u + 0x7fff + ((u >> 16) & 1)) >> 16;
    return (unsigned short)r;
}
// RTZ pack of two floats to one u32 of 2 bf16 (bias cancels in InstanceNorm)
__device__ __forceinline__ unsigned pkrtz(float a, float b) {
    return (__float_as_uint(a) >> 16) | (__float_as_uint(b) & 0xffff0000u);
}

// ---------------------------------------------------------------------------
// Setup: pre-transpose weights to bf16 wsW[g][o][32]  (kk = ch*16 + k, pads 0)
// ---------------------------------------------------------------------------
__global__ void setup_w(const float* __restrict__ wgt, float* __restrict__ ws) {
    unsigned short* wsW = (unsigned short*)(ws + WS_W);
    const int g = blockIdx.x;          // channel pair 0..31
    const int t = threadIdx.x;         // 256
    const int o = t >> 2;
    const int k0 = (t & 3) * 8;
#pragma unroll
    for (int j = 0; j < 8; ++j) {
        int kk = k0 + j;
        int ch = kk >> 4, k = kk & 15;
        float v = (k < 9) ? wgt[((size_t)o * CIN + 2 * g + ch) * 9 + k] : 0.f;
        wsW[g * 2048 + o * 32 + kk] = f2bf_rne(v);
    }
}

// ---------------------------------------------------------------------------
// Fused upsample + DISCO conv. Block = 16x16 px tile, 512 threads, 8 waves.
// WAVE-SPECIALIZED: waves 0-3 = compute (zphase + MFMA + acc), waves 4-7 =
// memory (cload/cwrite/fine_build). Same 1-barrier parity schedule as R9 --
// phases that were serialized per-thread now run on different waves
// concurrently. Compute-path regs ~112 <= 128 -> 4 waves/SIMD (2 blk/CU).
// ---------------------------------------------------------------------------
__global__ __launch_bounds__(512, 4) void conv_kernel(const float* __restrict__ img,
                                                      float* __restrict__ out,
                                                      float* __restrict__ ws) {
    __shared__ __align__(16) unsigned short zbuf[2][256][ZS]; // [buf][px][kk]
    __shared__ f32x2 halo[2][22 * HSX];        // [buf] {ch0,ch1} f32
    __shared__ f32x2 coarse[2][14 * 15];       // [buf] {ch0,ch1} f32
    __shared__ float red1[4][64], red2[4][64];

    const int tid  = threadIdx.x;
    const int bid  = blockIdx.x;
    const int n    = bid >> 8;
    const int tile = bid & 255;
    const int ty0  = (tile >> 4) << 4;
    const int tx0  = (tile & 15) << 4;

    const int w    = tid >> 6;         // wave 0..7
    const bool isC = (w < 4);          // compute waves
    const int l    = tid & 63;
    const int a16  = l & 15;
    const int kseg = (l >> 4) * 8;
    const int mtid = tid & 255;        // local id within the 256-thread half

    const unsigned short* wsW = (const unsigned short*)(ws + WS_W);

    // zero both zbuf buffers once (kk pads stay zero forever)
    {
        uint4* zr = (uint4*)&zbuf[0][0][0];
#pragma unroll
        for (int j = 0; j < 5; ++j) {
            int idx = tid + j * 512;
            if (idx < 2304) zr[idx] = make_uint4(0, 0, 0, 0);
        }
    }

    const float cs = 0.49803922f;   // 127/255

    // ---- block-constant coarse patch base ----
    int cy0 = (int)floorf((float)(ty0 - 3) * cs); cy0 = min(max(cy0, 0), 114);
    int cx0 = (int)floorf((float)(tx0 - 3) * cs); cx0 = min(max(cx0, 0), 114);

    // ================= memory-wave state (waves 4-7) =================
    bool cok = false;
    int cgoff = 0, cwidx = 0;
    float cv0 = 0.f, cv1 = 0.f;
    unsigned fM[2] = {0, 0};
    float fFY[2] = {0.f, 0.f}, fFX[2] = {0.f, 0.f};

    if (!isC) {
        cok = mtid < 196;
        int ci = mtid / 14, cj = mtid - ci * 14;
        cgoff = (cy0 + ci) * W + (cx0 + cj);
        cwidx = ci * 15 + cj;
#pragma unroll
        for (int j = 0; j < 2; ++j) {
            int e = mtid + j * 256;
            if (e < 484) {
                int hy = e / 22, hx = e - hy * 22;
                int uy = ty0 - 3 + hy, ux = tx0 - 3 + hx;
                unsigned zf = (((unsigned)uy >= 256u) || ((unsigned)ux >= 256u)) ? 1u : 0u;
                float syf = (float)uy * cs;
                float sxf = (float)ux * cs;
                int y0 = (int)floorf(syf);
                int x0 = (int)floorf(sxf);
                fFY[j] = syf - (float)y0;
                fFX[j] = sxf - (float)x0;
                int y0c = min(max(y0, 0), 127), x0c = min(max(x0, 0), 127);
                int dyo = min(y0c + 1, 127) - y0c;
                int dxo = min(x0c + 1, 127) - x0c;
                unsigned A = (unsigned)((y0c - cy0) * 15 + (x0c - cx0));
                fM[j] = A | ((unsigned)dxo << 9) | ((unsigned)dyo << 10) | (zf << 11)
                          | ((unsigned)(hy * HSX + hx) << 12);
            }
        }
    }

    auto cload = [&](int g) {
        if (cok) {
            const float* b = img + ((size_t)n * CIN + 2 * g) * (H * W) + cgoff;
            cv0 = b[0];
            cv1 = b[H * W];
        }
    };
    auto cwrite = [&](int q) {
        if (cok) coarse[q][cwidx] = (f32x2){cv0, cv1};
    };
    auto fine_build = [&](int q) {
#pragma unroll
        for (int j = 0; j < 2; ++j)
            if (mtid < 484 - j * 256) {
                unsigned m = fM[j];
                const f32x2* cb = &coarse[q][0];
                int A = m & 511;
                int dxo = (m >> 9) & 1;
                int dyo = ((m >> 10) & 1) * 15;
                f32x2 c00 = cb[A],       c01 = cb[A + dxo];
                f32x2 c10 = cb[A + dyo], c11 = cb[A + dyo + dxo];
                f32x2 fyv = (f32x2){fFY[j], fFY[j]};
                f32x2 fxv = (f32x2){fFX[j], fFX[j]};
                f32x2 t0 = c00 + fyv * (c10 - c00);
                f32x2 t1 = c01 + fyv * (c11 - c01);
                f32x2 v  = t0 + fxv * (t1 - t0);
                if (m & (1u << 11)) v = (f32x2){0.f, 0.f};
                halo[q][m >> 12] = v;
            }
    };

    // ================= compute-wave state (waves 0-3) =================
    const int r = mtid >> 4, c = mtid & 15;
    const int hbase = (r + 3) * HSX + (c + 3);

    auto zphase = [&](int p) {
        const f32x2* hb = &halo[p][hbase - 72];   // all imm offsets >= 0
        f32x2 z[9];
#pragma unroll
        for (int k = 0; k < 9; ++k) z[k] = (f32x2){0.f, 0.f};
#pragma unroll
        for (int t = 0; t < NT; ++t) {
            f32x2 h = hb[72 + TT.off[t]];
#pragma unroll
            for (int k = 0; k < 9; ++k)
                if (TT.nz[t][k]) z[k] += h * TT.val[t][k];   // v_pk_fma_f32
        }
        unsigned short* zr = &zbuf[p][mtid][0];
        ((uint2*)zr)[0] = make_uint2(pkrtz(z[0].x, z[1].x), pkrtz(z[2].x, z[3].x));
        ((uint2*)zr)[1] = make_uint2(pkrtz(z[4].x, z[5].x), pkrtz(z[6].x, z[7].x));
        zr[8] = (unsigned short)(__float_as_uint(z[8].x) >> 16);
        ((uint2*)(zr + 16))[0] = make_uint2(pkrtz(z[0].y, z[1].y), pkrtz(z[2].y, z[3].y));
        ((uint2*)(zr + 16))[1] = make_uint2(pkrtz(z[4].y, z[5].y), pkrtz(z[6].y, z[7].y));
        zr[24] = (unsigned short)(__float_as_uint(z[8].y) >> 16);
    };

    f32x4 acc[4][4];
#pragma unroll
    for (int m = 0; m < 4; ++m)
#pragma unroll
        for (int t = 0; t < 4; ++t) acc[m][t] = (f32x4){0.f, 0.f, 0.f, 0.f};

    // ---- prologue (R9 schedule, memory waves execute the staging) ----
    if (!isC) { cload(0); cwrite(0); }
    __syncthreads();
    if (!isC) { fine_build(0); cload(1); }
    __syncthreads();
    if (!isC) { cwrite(1); cload(2); }
    __syncthreads();

#pragma unroll 1
    for (int i = 0; i <= 32; ++i) {
        if (isC) {
            // MFMA for pair i-1 from zbuf[(i-1)&1]
            if (i >= 1) {
                const int zp = (i - 1) & 1;
                bf16x8 af[4];
                const unsigned short* wp = wsW + (i - 1) * 2048 + a16 * 32 + kseg;
#pragma unroll
                for (int m = 0; m < 4; ++m)
                    af[m] = *(const bf16x8*)(wp + m * 512);
                union { uint2 q2[2]; bf16x8 v; } bfr;
#pragma unroll
                for (int t = 0; t < 4; ++t) {
                    const unsigned short* zp2 = &zbuf[zp][w * 64 + t * 16 + a16][kseg];
                    bfr.q2[0] = *(const uint2*)zp2;
                    bfr.q2[1] = *(const uint2*)(zp2 + 4);
#pragma unroll
                    for (int m = 0; m < 4; ++m)
                        acc[m][t] = __builtin_amdgcn_mfma_f32_16x16x32_bf16(af[m], bfr.v, acc[m][t], 0, 0, 0);
                }
            }
            if (i < 32) zphase(i & 1);           // halo[i&1] -> zbuf[i&1]
        } else {
            if (i <= 29) cwrite(i & 1);          // regs(pair i+2) -> coarse[i&1]
            if (i <= 30) fine_build((i + 1) & 1);// coarse[(i+1)&1] -> halo[(i+1)&1]
            if (i <= 28) cload(i + 3);           // global -> regs (pair i+3)
        }
        __syncthreads();
    }

    // ---- epilogue: instance-norm partials + store y (compute waves) ----
    if (isC) {
#pragma unroll
        for (int m = 0; m < 4; ++m) {
#pragma unroll
            for (int r4 = 0; r4 < 4; ++r4) {
                float s = 0.f, q = 0.f;
#pragma unroll
                for (int t = 0; t < 4; ++t) {
                    float v = acc[m][t][r4];
                    s += v; q = fmaf(v, v, q);
                }
#pragma unroll
                for (int msk = 1; msk < 16; msk <<= 1) {
                    s += __shfl_xor(s, msk);
                    q += __shfl_xor(q, msk);
                }
                if (a16 == 0) {
                    int o = m * 16 + (l >> 4) * 4 + r4;
                    red1[w][o] = s;
                    red2[w][o] = q;
                }
            }
        }
        const size_t nbase = (size_t)n * COUT * (H2 * W2);
#pragma unroll
        for (int m = 0; m < 4; ++m)
#pragma unroll
            for (int t = 0; t < 4; ++t) {
                int Y = ty0 + w * 4 + t;
                int X = tx0 + a16;
#pragma unroll
                for (int r4 = 0; r4 < 4; ++r4) {
                    int o = m * 16 + (l >> 4) * 4 + r4;
                    out[nbase + (size_t)o * (H2 * W2) + Y * W2 + X] = acc[m][t][r4];
                }
            }
    }
    __syncthreads();
    if (tid < 64) {
        float S1 = red1[0][tid] + red1[1][tid] + red1[2][tid] + red1[3][tid];
        float S2 = red2[0][tid] + red2[1][tid] + red2[2][tid] + red2[3][tid];
        ws[WS_P1 + (n * COUT + tid) * 256 + tile] = S1;
        ws[WS_P2 + (n * COUT + tid) * 256 + tile] = S2;
    }
}

// ---------------------------------------------------------------------------
// Stats: reduce 256 tile-partials per (n,c)
// ---------------------------------------------------------------------------
__global__ void stats_kernel(float* __restrict__ ws) {
    const int co  = blockIdx.x;
    const int tid = threadIdx.x;   // 256
    float s1 = ws[WS_P1 + co * 256 + tid];
    float s2 = ws[WS_P2 + co * 256 + tid];
#pragma unroll
    for (int m = 1; m < 64; m <<= 1) { s1 += __shfl_xor(s1, m); s2 += __shfl_xor(s2, m); }
    __shared__ float r1[4], r2[4];
    if ((tid & 63) == 0) { r1[tid >> 6] = s1; r2[tid >> 6] = s2; }
    __syncthreads();
    if (tid == 0) {
        float S1 = r1[0] + r1[1] + r1[2] + r1[3];
        float S2 = r2[0] + r2[1] + r2[2] + r2[3];
        const float inv = 1.f / 65536.f;
        float mu  = S1 * inv;
        float var = S2 * inv - mu * mu;
        ws[WS_MU + co]   = mu;
        ws[WS_RSTD + co] = 1.f / sqrtf(var + 1e-5f);
    }
}

// ---------------------------------------------------------------------------
// Normalize + LeakyReLU(0.2), in place on d_out
// ---------------------------------------------------------------------------
__global__ void norm_kernel(float* __restrict__ out, const float* __restrict__ ws) {
    const int total = NB * COUT * H2 * W2 / 4;
    for (int idx = blockIdx.x * blockDim.x + threadIdx.x; idx < total;
         idx += gridDim.x * blockDim.x) {
        int co = idx >> 14;
        float mu = ws[WS_MU + co];
        float rs = ws[WS_RSTD + co];
        float4 v = ((float4*)out)[idx];
        float* p = (float*)&v;
#pragma unroll
        for (int j = 0; j < 4; ++j) {
            float t = (p[j] - mu) * rs;
            p[j] = (t >= 0.f) ? t : 0.2f * t;
        }
        ((float4*)out)[idx] = v;
    }
}

extern "C" void kernel_launch(void* const* d_in, const int* in_sizes, int n_in,
                              void* d_out, int out_size, void* d_ws, size_t ws_size,
                              hipStream_t stream) {
    const float* img = (const float*)d_in[0];
    const float* wgt = (const float*)d_in[1];
    float* out = (float*)d_out;
    float* ws  = (float*)d_ws;

    setup_w<<<32, 256, 0, stream>>>(wgt, ws);
    conv_kernel<<<NB * 256, 512, 0, stream>>>(img, out, ws);
    stats_kernel<<<256, 256, 0, stream>>>(ws);
    norm_kernel<<<2048, 256, 0, stream>>>(out, ws);
}

// Round 14
// 226.244 us; speedup vs baseline: 1.9594x; 1.9594x over previous
//
#include <hip/hip_runtime.h>

#define NB 4
#define CIN 64
#define COUT 64
#define H 128
#define W 128
#define H2 256
#define W2 256
#define HSX 23            // halo row stride (f32x2 units)
#define ZS 36             // zbuf row stride (ushorts) = 72B

// ws layout (float units)
#define WS_W    0         // bf16 weights ushort[32][64][32] = 32768 floats
#define WS_P1   32768     // per-tile partial sums  [4*64][256]
#define WS_P2   98304     // per-tile partial sumsq [4*64][256]
#define WS_MU   163840
#define WS_RSTD 164096

// ---------------------------------------------------------------------------
// Compile-time DISCO basis (replicates the numpy double-precision computation)
// ---------------------------------------------------------------------------
constexpr double csqrt(double x) {
    double g = x > 1.0 ? x : 1.0;
    for (int i = 0; i < 64; ++i) g = 0.5 * (g + x / g);
    return g;
}
constexpr double catan_pos(double x) {
    double f = 1.0;
    for (int i = 0; i < 6; ++i) { x = x / (1.0 + csqrt(1.0 + x * x)); f *= 2.0; }
    double x2 = x * x, s = 0.0, term = x;
    for (int n = 0; n < 10; ++n) { s += term / (2 * n + 1) * ((n & 1) ? -1.0 : 1.0); term *= x2; }
    return f * s;
}
constexpr double catan2c(double y, double x) {
    const double PI = 3.141592653589793;
    if (x == 0.0 && y == 0.0) return 0.0;
    double ax = x < 0 ? -x : x, ay = y < 0 ? -y : y;
    double a = (ax >= ay) ? catan_pos(ay / ax) : (PI / 2.0 - catan_pos(ax / ay));
    if (x < 0) a = PI - a;
    return (y < 0) ? -a : a;
}

struct PsiTab { double v[81][9]; };
constexpr PsiTab compute_psi() {
    PsiTab P{};
    const double hy = 1.0 / 256.0;
    const double rcut = 0.015;
    const double dr = 0.0075;
    const double PI = 3.141592653589793;
    const double TWO_PI = 6.283185307179586;
    const double dphi = PI / 2.0;
    for (int ky = 0; ky < 9; ++ky)
        for (int kx = 0; kx < 9; ++kx) {
            double dy = (double)(ky - 4) * hy;
            double dx = (double)(kx - 4) * hy;
            double r = csqrt(dy * dy + dx * dx);
            double phi = catan2c(dy, dx);
            if (phi < 0.0) phi += TWO_PI;
            for (int k = 0; k < 9; ++k) {
                int ir = (k == 0) ? 0 : ((k - 1) / 4 + 1);
                double ctr = ir * dr;
                double ad = r > ctr ? r - ctr : ctr - r;
                double rv = (ad <= dr && r <= rcut) ? 1.0 - ad / dr : 0.0;
                double val;
                if (k == 0) val = rv;
                else {
                    int ip = (k - 1) % 4;
                    double da = phi - ip * dphi; if (da < 0) da = -da;
                    double d2 = TWO_PI - da; if (d2 < da) da = d2;
                    double pv = (da <= dphi) ? 1.0 - da / dphi : 0.0;
                    val = rv * pv;
                }
                P.v[ky * 9 + kx][k] = val * (hy * hy);
            }
        }
    return P;
}

struct TapTab {
    int nt;
    int off[48];          // dy*HSX + dx (f32x2 offset from thread base)
    float val[48][9];
    bool nz[48][9];
};
constexpr TapTab make_taps() {
    TapTab T{};
    PsiTab P = compute_psi();
    for (int ky = 0; ky < 9; ++ky)
        for (int kx = 0; kx < 9; ++kx) {
            int t = ky * 9 + kx;
            bool any = false;
            for (int k = 0; k < 9; ++k) if (P.v[t][k] != 0.0) any = true;
            if (!any) continue;
            int dy = ky - 4, dx = kx - 4;    // support guarantees |dy|,|dx| <= 3
            T.off[T.nt] = dy * HSX + dx;
            for (int k = 0; k < 9; ++k) {
                T.val[T.nt][k] = (float)P.v[t][k];
                T.nz[T.nt][k] = (P.v[t][k] != 0.0);
            }
            T.nt++;
        }
    return T;
}
constexpr TapTab TT = make_taps();
constexpr int NT = TT.nt;
static_assert(NT > 0 && NT <= 48, "tap table overflow");

using f32x2  = __attribute__((ext_vector_type(2))) float;
using f32x4  = __attribute__((ext_vector_type(4))) float;
using bf16x8 = __attribute__((ext_vector_type(8))) short;

__device__ __forceinline__ unsigned short f2bf_rne(float f) {
    unsigned u = __float_as_uint(f);
    unsigned r = (u + 0x7fff + ((u >> 16) & 1)) >> 16;
    return (unsigned short)r;
}
// RTZ pack of two floats to one u32 of 2 bf16 (bias cancels in InstanceNorm)
__device__ __forceinline__ unsigned pkrtz(float a, float b) {
    return (__float_as_uint(a) >> 16) | (__float_as_uint(b) & 0xffff0000u);
}

// ---------------------------------------------------------------------------
// Setup: pre-transpose weights to bf16 wsW[g][o][32]  (kk = ch*16 + k, pads 0)
// ---------------------------------------------------------------------------
__global__ void setup_w(const float* __restrict__ wgt, float* __restrict__ ws) {
    unsigned short* wsW = (unsigned short*)(ws + WS_W);
    const int g = blockIdx.x;          // channel pair 0..31
    const int t = threadIdx.x;         // 256
    const int o = t >> 2;
    const int k0 = (t & 3) * 8;
#pragma unroll
    for (int j = 0; j < 8; ++j) {
        int kk = k0 + j;
        int ch = kk >> 4, k = kk & 15;
        float v = (k < 9) ? wgt[((size_t)o * CIN + 2 * g + ch) * 9 + k] : 0.f;
        wsW[g * 2048 + o * 32 + kk] = f2bf_rne(v);
    }
}

// ---------------------------------------------------------------------------
// Fused upsample + DISCO conv. Block = 16x16 px tile (256 px), 4 waves.
// R9 structure exactly; ONLY change: __launch_bounds__(256,3) -- declares
// 3 waves/EU residency (reg cap 170 >= our 160, so codegen unchanged).
// Probe: does occupancy rise 2->3 waves/SIMD, or does HW reg quantum block it?
// ---------------------------------------------------------------------------
__global__ __launch_bounds__(256, 3) void conv_kernel(const float* __restrict__ img,
                                                      float* __restrict__ out,
                                                      float* __restrict__ ws) {
    __shared__ __align__(16) unsigned short zbuf[2][256][ZS]; // [buf][px][kk]
    __shared__ f32x2 halo[2][22 * HSX];        // [buf] {ch0,ch1} f32
    __shared__ f32x2 coarse[2][14 * 15];       // [buf] {ch0,ch1} f32
    __shared__ float red1[4][64], red2[4][64];

    const int tid  = threadIdx.x;
    const int bid  = blockIdx.x;
    const int n    = bid >> 8;
    const int tile = bid & 255;
    const int ty0  = (tile >> 4) << 4;
    const int tx0  = (tile & 15) << 4;

    const int r = tid >> 4, c = tid & 15;
    const int hbase = (r + 3) * HSX + (c + 3);
    const int wv  = tid >> 6;
    const int l   = tid & 63;
    const int a16 = l & 15;
    const int kseg = (l >> 4) * 8;

    const unsigned short* wsW = (const unsigned short*)(ws + WS_W);

    // zero both zbuf buffers once (kk pads stay zero forever)
    {
        uint4* zr = (uint4*)&zbuf[0][0][0];
#pragma unroll
        for (int j = 0; j < 9; ++j) zr[tid + j * 256] = make_uint4(0, 0, 0, 0);
    }

    const float cs = 0.49803922f;   // 127/255

    // ---- block-constant coarse patch base ----
    int cy0 = (int)floorf((float)(ty0 - 3) * cs); cy0 = min(max(cy0, 0), 114);
    int cx0 = (int)floorf((float)(tx0 - 3) * cs); cx0 = min(max(cx0, 0), 114);

    // ---- coarse loader invariants (1 elem/thread, 196 used) ----
    const bool cok = tid < 196;
    const int ci = tid / 14, cj = tid - ci * 14;
    const int cgoff = (cy0 + ci) * W + (cx0 + cj);
    const int cwidx = ci * 15 + cj;
    float cv0 = 0.f, cv1 = 0.f;

    auto cload = [&](int g) {
        if (cok) {
            const float* b = img + ((size_t)n * CIN + 2 * g) * (H * W) + cgoff;
            cv0 = b[0];
            cv1 = b[H * W];
        }
    };
    auto cwrite = [&](int q) {
        if (cok) coarse[q][cwidx] = (f32x2){cv0, cv1};
    };

    // ---- fine-halo metadata: 484 elems, 2 slots, packed u32 + fy + fx ----
    unsigned fM[2];
    float fFY[2], fFX[2];
#pragma unroll
    for (int j = 0; j < 2; ++j) {
        int e = tid + j * 256;
        if (e < 484) {
            int hy = e / 22, hx = e - hy * 22;
            int uy = ty0 - 3 + hy, ux = tx0 - 3 + hx;
            unsigned zf = (((unsigned)uy >= 256u) || ((unsigned)ux >= 256u)) ? 1u : 0u;
            float syf = (float)uy * cs;
            float sxf = (float)ux * cs;
            int y0 = (int)floorf(syf);
            int x0 = (int)floorf(sxf);
            fFY[j] = syf - (float)y0;
            fFX[j] = sxf - (float)x0;
            int y0c = min(max(y0, 0), 127), x0c = min(max(x0, 0), 127);
            int dyo = min(y0c + 1, 127) - y0c;            // 0/1
            int dxo = min(x0c + 1, 127) - x0c;            // 0/1
            unsigned A = (unsigned)((y0c - cy0) * 15 + (x0c - cx0));
            fM[j] = A | ((unsigned)dxo << 9) | ((unsigned)dyo << 10) | (zf << 11)
                      | ((unsigned)(hy * HSX + hx) << 12);
        }
    }

    auto fine_build = [&](int q) {
#pragma unroll
        for (int j = 0; j < 2; ++j)
            if (tid < 484 - j * 256) {
                unsigned m = fM[j];
                const f32x2* cb = &coarse[q][0];
                int A = m & 511;
                int dxo = (m >> 9) & 1;
                int dyo = ((m >> 10) & 1) * 15;
                f32x2 c00 = cb[A],       c01 = cb[A + dxo];
                f32x2 c10 = cb[A + dyo], c11 = cb[A + dyo + dxo];
                f32x2 fyv = (f32x2){fFY[j], fFY[j]};
                f32x2 fxv = (f32x2){fFX[j], fFX[j]};
                f32x2 t0 = c00 + fyv * (c10 - c00);
                f32x2 t1 = c01 + fyv * (c11 - c01);
                f32x2 v  = t0 + fxv * (t1 - t0);
                if (m & (1u << 11)) v = (f32x2){0.f, 0.f};
                halo[q][m >> 12] = v;
            }
    };

    auto zphase = [&](int p) {
        const f32x2* hb = &halo[p][hbase - 72];   // all imm offsets >= 0
        f32x2 z[9];
#pragma unroll
        for (int k = 0; k < 9; ++k) z[k] = (f32x2){0.f, 0.f};
#pragma unroll
        for (int t = 0; t < NT; ++t) {
            f32x2 h = hb[72 + TT.off[t]];
#pragma unroll
            for (int k = 0; k < 9; ++k)
                if (TT.nz[t][k]) z[k] += h * TT.val[t][k];   // v_pk_fma_f32
        }
        unsigned short* zr = &zbuf[p][tid][0];
        ((uint2*)zr)[0] = make_uint2(pkrtz(z[0].x, z[1].x), pkrtz(z[2].x, z[3].x));
        ((uint2*)zr)[1] = make_uint2(pkrtz(z[4].x, z[5].x), pkrtz(z[6].x, z[7].x));
        zr[8] = (unsigned short)(__float_as_uint(z[8].x) >> 16);
        ((uint2*)(zr + 16))[0] = make_uint2(pkrtz(z[0].y, z[1].y), pkrtz(z[2].y, z[3].y));
        ((uint2*)(zr + 16))[1] = make_uint2(pkrtz(z[4].y, z[5].y), pkrtz(z[6].y, z[7].y));
        zr[24] = (unsigned short)(__float_as_uint(z[8].y) >> 16);
    };

    f32x4 acc[4][4];
#pragma unroll
    for (int m = 0; m < 4; ++m)
#pragma unroll
        for (int t = 0; t < 4; ++t) acc[m][t] = (f32x4){0.f, 0.f, 0.f, 0.f};

    // ---- prologue: coarse[0]=pair0, halo[0]=pair0, coarse[1]=pair1, regs=pair2
    cload(0); cwrite(0);
    __syncthreads();
    fine_build(0);        // coarse[0] -> halo[0]
    cload(1);
    __syncthreads();
    cwrite(1);            // regs(pair1) -> coarse[1]
    cload(2);
    __syncthreads();

#pragma unroll 1
    for (int i = 0; i <= 32; ++i) {
        // matrix pipe first: MFMA for pair i-1 (zbuf[(i-1)&1], weights i-1)
        if (i >= 1) {
            const int zp = (i - 1) & 1;
            bf16x8 af[4];
            const unsigned short* wp = wsW + (i - 1) * 2048 + a16 * 32 + kseg;
#pragma unroll
            for (int m = 0; m < 4; ++m)
                af[m] = *(const bf16x8*)(wp + m * 512);
            union { uint2 q2[2]; bf16x8 v; } bfr;
#pragma unroll
            for (int t = 0; t < 4; ++t) {
                const unsigned short* zp2 = &zbuf[zp][wv * 64 + t * 16 + a16][kseg];
                bfr.q2[0] = *(const uint2*)zp2;
                bfr.q2[1] = *(const uint2*)(zp2 + 4);
#pragma unroll
                for (int m = 0; m < 4; ++m)
                    acc[m][t] = __builtin_amdgcn_mfma_f32_16x16x32_bf16(af[m], bfr.v, acc[m][t], 0, 0, 0);
            }
        }
        if (i < 32)  zphase(i & 1);          // halo[i&1] -> zbuf[i&1]   (pair i)
        if (i <= 29) cwrite(i & 1);          // regs(pair i+2) -> coarse[i&1]
        if (i <= 30) fine_build((i + 1) & 1);// coarse[(i+1)&1] -> halo[(i+1)&1]
        if (i <= 28) cload(i + 3);           // global -> regs (pair i+3)
        __syncthreads();
    }

    // ---- epilogue: instance-norm partials + store y ----
#pragma unroll
    for (int m = 0; m < 4; ++m) {
#pragma unroll
        for (int r4 = 0; r4 < 4; ++r4) {
            float s = 0.f, q = 0.f;
#pragma unroll
            for (int t = 0; t < 4; ++t) {
                float v = acc[m][t][r4];
                s += v; q = fmaf(v, v, q);
            }
#pragma unroll
            for (int msk = 1; msk < 16; msk <<= 1) {
                s += __shfl_xor(s, msk);
                q += __shfl_xor(q, msk);
            }
            if (a16 == 0) {
                int o = m * 16 + (l >> 4) * 4 + r4;
                red1[wv][o] = s;
                red2[wv][o] = q;
            }
        }
    }

    const size_t nbase = (size_t)n * COUT * (H2 * W2);
#pragma unroll
    for (int m = 0; m < 4; ++m)
#pragma unroll
        for (int t = 0; t < 4; ++t) {
            int Y = ty0 + wv * 4 + t;
            int X = tx0 + a16;
#pragma unroll
            for (int r4 = 0; r4 < 4; ++r4) {
                int o = m * 16 + (l >> 4) * 4 + r4;
                out[nbase + (size_t)o * (H2 * W2) + Y * W2 + X] = acc[m][t][r4];
            }
        }
    __syncthreads();
    if (tid < 64) {
        float S1 = red1[0][tid] + red1[1][tid] + red1[2][tid] + red1[3][tid];
        float S2 = red2[0][tid] + red2[1][tid] + red2[2][tid] + red2[3][tid];
        ws[WS_P1 + (n * COUT + tid) * 256 + tile] = S1;
        ws[WS_P2 + (n * COUT + tid) * 256 + tile] = S2;
    }
}

// ---------------------------------------------------------------------------
// Stats: reduce 256 tile-partials per (n,c)
// ---------------------------------------------------------------------------
__global__ void stats_kernel(float* __restrict__ ws) {
    const int co  = blockIdx.x;
    const int tid = threadIdx.x;   // 256
    float s1 = ws[WS_P1 + co * 256 + tid];
    float s2 = ws[WS_P2 + co * 256 + tid];
#pragma unroll
    for (int m = 1; m < 64; m <<= 1) { s1 += __shfl_xor(s1, m); s2 += __shfl_xor(s2, m); }
    __shared__ float r1[4], r2[4];
    if ((tid & 63) == 0) { r1[tid >> 6] = s1; r2[tid >> 6] = s2; }
    __syncthreads();
    if (tid == 0) {
        float S1 = r1[0] + r1[1] + r1[2] + r1[3];
        float S2 = r2[0] + r2[1] + r2[2] + r2[3];
        const float inv = 1.f / 65536.f;
        float mu  = S1 * inv;
        float var = S2 * inv - mu * mu;
        ws[WS_MU + co]   = mu;
        ws[WS_RSTD + co] = 1.f / sqrtf(var + 1e-5f);
    }
}

// ---------------------------------------------------------------------------
// Normalize + LeakyReLU(0.2), in place on d_out
// ---------------------------------------------------------------------------
__global__ void norm_kernel(float* __restrict__ out, const float* __restrict__ ws) {
    const int total = NB * COUT * H2 * W2 / 4;
    for (int idx = blockIdx.x * blockDim.x + threadIdx.x; idx < total;
         idx += gridDim.x * blockDim.x) {
        int co = idx >> 14;
        float mu = ws[WS_MU + co];
        float rs = ws[WS_RSTD + co];
        float4 v = ((float4*)out)[idx];
        float* p = (float*)&v;
#pragma unroll
        for (int j = 0; j < 4; ++j) {
            float t = (p[j] - mu) * rs;
            p[j] = (t >= 0.f) ? t : 0.2f * t;
        }
        ((float4*)out)[idx] = v;
    }
}

extern "C" void kernel_launch(void* const* d_in, const int* in_sizes, int n_in,
                              void* d_out, int out_size, void* d_ws, size_t ws_size,
                              hipStream_t stream) {
    const float* img = (const float*)d_in[0];
    const float* wgt = (const float*)d_in[1];
    float* out = (float*)d_out;
    float* ws  = (float*)d_ws;

    setup_w<<<32, 256, 0, stream>>>(wgt, ws);
    conv_kernel<<<NB * 256, 256, 0, stream>>>(img, out, ws);
    stats_kernel<<<256, 256, 0, stream>>>(ws);
    norm_kernel<<<2048, 256, 0, stream>>>(out, ws);
}

// Round 15
// 213.790 us; speedup vs baseline: 2.0735x; 1.0583x over previous
//
#include <hip/hip_runtime.h>

#define NB 4
#define CIN 64
#define COUT 64
#define H 128
#define W 128
#define H2 256
#define W2 256
#define HSX 23            // halo row stride (f32x2 units)
#define ZS 36             // zbuf row stride (ushorts) = 72B

// ws layout (float units)
#define WS_W    0         // bf16 weights ushort[32][64][32] = 32768 floats
#define WS_P1   32768     // per-tile partial sums  [4*64][256]
#define WS_P2   98304     // per-tile partial sumsq [4*64][256]
#define WS_MU   163840
#define WS_RSTD 164096

// ---------------------------------------------------------------------------
// Compile-time DISCO basis (replicates the numpy double-precision computation)
// ---------------------------------------------------------------------------
constexpr double csqrt(double x) {
    double g = x > 1.0 ? x : 1.0;
    for (int i = 0; i < 64; ++i) g = 0.5 * (g + x / g);
    return g;
}
constexpr double catan_pos(double x) {
    double f = 1.0;
    for (int i = 0; i < 6; ++i) { x = x / (1.0 + csqrt(1.0 + x * x)); f *= 2.0; }
    double x2 = x * x, s = 0.0, term = x;
    for (int n = 0; n < 10; ++n) { s += term / (2 * n + 1) * ((n & 1) ? -1.0 : 1.0); term *= x2; }
    return f * s;
}
constexpr double catan2c(double y, double x) {
    const double PI = 3.141592653589793;
    if (x == 0.0 && y == 0.0) return 0.0;
    double ax = x < 0 ? -x : x, ay = y < 0 ? -y : y;
    double a = (ax >= ay) ? catan_pos(ay / ax) : (PI / 2.0 - catan_pos(ax / ay));
    if (x < 0) a = PI - a;
    return (y < 0) ? -a : a;
}

struct PsiTab { double v[81][9]; };
constexpr PsiTab compute_psi() {
    PsiTab P{};
    const double hy = 1.0 / 256.0;
    const double rcut = 0.015;
    const double dr = 0.0075;
    const double PI = 3.141592653589793;
    const double TWO_PI = 6.283185307179586;
    const double dphi = PI / 2.0;
    for (int ky = 0; ky < 9; ++ky)
        for (int kx = 0; kx < 9; ++kx) {
            double dy = (double)(ky - 4) * hy;
            double dx = (double)(kx - 4) * hy;
            double r = csqrt(dy * dy + dx * dx);
            double phi = catan2c(dy, dx);
            if (phi < 0.0) phi += TWO_PI;
            for (int k = 0; k < 9; ++k) {
                int ir = (k == 0) ? 0 : ((k - 1) / 4 + 1);
                double ctr = ir * dr;
                double ad = r > ctr ? r - ctr : ctr - r;
                double rv = (ad <= dr && r <= rcut) ? 1.0 - ad / dr : 0.0;
                double val;
                if (k == 0) val = rv;
                else {
                    int ip = (k - 1) % 4;
                    double da = phi - ip * dphi; if (da < 0) da = -da;
                    double d2 = TWO_PI - da; if (d2 < da) da = d2;
                    double pv = (da <= dphi) ? 1.0 - da / dphi : 0.0;
                    val = rv * pv;
                }
                P.v[ky * 9 + kx][k] = val * (hy * hy);
            }
        }
    return P;
}

struct TapTab {
    int nt;
    int off[48];          // dy*HSX + dx (f32x2 offset from thread base)
    float val[48][9];
    bool nz[48][9];
};
constexpr TapTab make_taps() {
    TapTab T{};
    PsiTab P = compute_psi();
    for (int ky = 0; ky < 9; ++ky)
        for (int kx = 0; kx < 9; ++kx) {
            int t = ky * 9 + kx;
            bool any = false;
            for (int k = 0; k < 9; ++k) if (P.v[t][k] != 0.0) any = true;
            if (!any) continue;
            int dy = ky - 4, dx = kx - 4;    // support guarantees |dy|,|dx| <= 3
            T.off[T.nt] = dy * HSX + dx;
            for (int k = 0; k < 9; ++k) {
                T.val[T.nt][k] = (float)P.v[t][k];
                T.nz[T.nt][k] = (P.v[t][k] != 0.0);
            }
            T.nt++;
        }
    return T;
}
constexpr TapTab TT = make_taps();
constexpr int NT = TT.nt;
static_assert(NT == 45, "expected 45 taps");
#define NTA 23            // sub0 handles taps [0,23), sub1 handles [23,45)

using f32x2  = __attribute__((ext_vector_type(2))) float;
using f32x4  = __attribute__((ext_vector_type(4))) float;
using bf16x8 = __attribute__((ext_vector_type(8))) short;

__device__ __forceinline__ unsigned short f2bf_rne(float f) {
    unsigned u = __float_as_uint(f);
    unsigned r = (u + 0x7fff + ((u >> 16) & 1)) >> 16;
    return (unsigned short)r;
}
// RTZ pack of two floats to one u32 of 2 bf16 (bias cancels in InstanceNorm)
__device__ __forceinline__ unsigned pkrtz(float a, float b) {
    return (__float_as_uint(a) >> 16) | (__float_as_uint(b) & 0xffff0000u);
}

// ---------------------------------------------------------------------------
// Setup: pre-transpose weights to bf16 wsW[g][o][32]  (kk = ch*16 + k, pads 0)
// ---------------------------------------------------------------------------
__global__ void setup_w(const float* __restrict__ wgt, float* __restrict__ ws) {
    unsigned short* wsW = (unsigned short*)(ws + WS_W);
    const int g = blockIdx.x;          // channel pair 0..31
    const int t = threadIdx.x;         // 256
    const int o = t >> 2;
    const int k0 = (t & 3) * 8;
#pragma unroll
    for (int j = 0; j < 8; ++j) {
        int kk = k0 + j;
        int ch = kk >> 4, k = kk & 15;
        float v = (k < 9) ? wgt[((size_t)o * CIN + 2 * g + ch) * 9 + k] : 0.f;
        wsW[g * 2048 + o * 32 + kk] = f2bf_rne(v);
    }
}

// ---------------------------------------------------------------------------
// Fused upsample + DISCO conv. Block = 16x16 px tile, 512 threads (8 waves).
// TAP-SPLIT: thread pair (px in waves0-3, px in waves4-7) splits the 45-tap
// list 23/22; sub1 writes partial z to pbuf, sub0 combines after barrier.
// Each wave owns 32px x 64o -> acc = 32 AGPR; z = 18 VGPR; staging on sub1.
// Per-wave regs ~ <=128 -> 4 waves/SIMD (launch_bounds 512,4), 2 blocks/CU.
// ---------------------------------------------------------------------------
__global__ __launch_bounds__(512, 4) void conv_kernel(const float* __restrict__ img,
                                                      float* __restrict__ out,
                                                      float* __restrict__ ws) {
    __shared__ __align__(16) unsigned short zbuf[2][256][ZS]; // [buf][px][kk]
    __shared__ f32x2 halo[2][22 * HSX];        // [buf] {ch0,ch1} f32
    __shared__ f32x2 coarse[2][14 * 15];       // [buf] {ch0,ch1} f32
    __shared__ float pbuf[18][256];            // sub1 partial z (k*2+half)
    __shared__ float red1[8][64], red2[8][64];

    const int tid  = threadIdx.x;
    const int bid  = blockIdx.x;
    const int n    = bid >> 8;
    const int tile = bid & 255;
    const int ty0  = (tile >> 4) << 4;
    const int tx0  = (tile & 15) << 4;

    const int sub = tid >> 8;          // 0: waves 0-3, 1: waves 4-7 (uniform)
    const int px  = tid & 255;
    const int r = px >> 4, c = px & 15;
    const int hbase = (r + 3) * HSX + (c + 3);
    const int wv  = tid >> 6;          // wave 0..7
    const int l   = tid & 63;
    const int a16 = l & 15;
    const int kseg = (l >> 4) * 8;

    const unsigned short* wsW = (const unsigned short*)(ws + WS_W);

    // zero both zbuf buffers once (kk pads stay zero forever)
    {
        uint4* zr = (uint4*)&zbuf[0][0][0];
#pragma unroll
        for (int j = 0; j < 5; ++j) {
            int idx = tid + j * 512;
            if (idx < 2304) zr[idx] = make_uint4(0, 0, 0, 0);
        }
    }

    const float cs = 0.49803922f;   // 127/255

    // ---- block-constant coarse patch base ----
    int cy0 = (int)floorf((float)(ty0 - 3) * cs); cy0 = min(max(cy0, 0), 114);
    int cx0 = (int)floorf((float)(tx0 - 3) * cs); cx0 = min(max(cx0, 0), 114);

    // ================ staging state (sub1 only uses it) ================
    bool cok = false;
    int cgoff = 0, cwidx = 0;
    float cv0 = 0.f, cv1 = 0.f;
    unsigned fM[2] = {0, 0};
    float fFY[2] = {0.f, 0.f}, fFX[2] = {0.f, 0.f};

    if (sub == 1) {
        cok = px < 196;
        int ci = px / 14, cj = px - ci * 14;
        cgoff = (cy0 + ci) * W + (cx0 + cj);
        cwidx = ci * 15 + cj;
#pragma unroll
        for (int j = 0; j < 2; ++j) {
            int e = px + j * 256;
            if (e < 484) {
                int hy = e / 22, hx = e - hy * 22;
                int uy = ty0 - 3 + hy, ux = tx0 - 3 + hx;
                unsigned zf = (((unsigned)uy >= 256u) || ((unsigned)ux >= 256u)) ? 1u : 0u;
                float syf = (float)uy * cs;
                float sxf = (float)ux * cs;
                int y0 = (int)floorf(syf);
                int x0 = (int)floorf(sxf);
                fFY[j] = syf - (float)y0;
                fFX[j] = sxf - (float)x0;
                int y0c = min(max(y0, 0), 127), x0c = min(max(x0, 0), 127);
                int dyo = min(y0c + 1, 127) - y0c;
                int dxo = min(x0c + 1, 127) - x0c;
                unsigned A = (unsigned)((y0c - cy0) * 15 + (x0c - cx0));
                fM[j] = A | ((unsigned)dxo << 9) | ((unsigned)dyo << 10) | (zf << 11)
                          | ((unsigned)(hy * HSX + hx) << 12);
            }
        }
    }

    auto cload = [&](int g) {
        if (cok) {
            const float* b = img + ((size_t)n * CIN + 2 * g) * (H * W) + cgoff;
            cv0 = b[0];
            cv1 = b[H * W];
        }
    };
    auto cwrite = [&](int q) {
        if (cok) coarse[q][cwidx] = (f32x2){cv0, cv1};
    };
    auto fine_build = [&](int q) {
#pragma unroll
        for (int j = 0; j < 2; ++j)
            if (px < 484 - j * 256) {
                unsigned m = fM[j];
                const f32x2* cb = &coarse[q][0];
                int A = m & 511;
                int dxo = (m >> 9) & 1;
                int dyo = ((m >> 10) & 1) * 15;
                f32x2 c00 = cb[A],       c01 = cb[A + dxo];
                f32x2 c10 = cb[A + dyo], c11 = cb[A + dyo + dxo];
                f32x2 fyv = (f32x2){fFY[j], fFY[j]};
                f32x2 fxv = (f32x2){fFX[j], fFX[j]};
                f32x2 t0 = c00 + fyv * (c10 - c00);
                f32x2 t1 = c01 + fyv * (c11 - c01);
                f32x2 v  = t0 + fxv * (t1 - t0);
                if (m & (1u << 11)) v = (f32x2){0.f, 0.f};
                halo[q][m >> 12] = v;
            }
    };

    // ================ tap-split zphase ================
    auto partialA = [&](int p, f32x2* z) {     // sub0: taps [0,NTA)
        const f32x2* hb = &halo[p][hbase - 72];
#pragma unroll
        for (int k = 0; k < 9; ++k) z[k] = (f32x2){0.f, 0.f};
#pragma unroll
        for (int t = 0; t < NTA; ++t) {
            f32x2 h = hb[72 + TT.off[t]];
#pragma unroll
            for (int k = 0; k < 9; ++k)
                if (TT.nz[t][k]) z[k] += h * TT.val[t][k];
        }
    };
    auto partialB_store = [&](int p) {         // sub1: taps [NTA,45) -> pbuf
        const f32x2* hb = &halo[p][hbase - 72];
        f32x2 z[9];
#pragma unroll
        for (int k = 0; k < 9; ++k) z[k] = (f32x2){0.f, 0.f};
#pragma unroll
        for (int t = NTA; t < NT; ++t) {
            f32x2 h = hb[72 + TT.off[t]];
#pragma unroll
            for (int k = 0; k < 9; ++k)
                if (TT.nz[t][k]) z[k] += h * TT.val[t][k];
        }
#pragma unroll
        for (int k = 0; k < 9; ++k) {
            pbuf[2 * k][px]     = z[k].x;
            pbuf[2 * k + 1][px] = z[k].y;
        }
    };
    auto combine_store = [&](int p, f32x2* z) { // sub0: add pbuf, pack, zbuf
#pragma unroll
        for (int k = 0; k < 9; ++k) {
            z[k].x += pbuf[2 * k][px];
            z[k].y += pbuf[2 * k + 1][px];
        }
        unsigned short* zr = &zbuf[p][px][0];
        ((uint2*)zr)[0] = make_uint2(pkrtz(z[0].x, z[1].x), pkrtz(z[2].x, z[3].x));
        ((uint2*)zr)[1] = make_uint2(pkrtz(z[4].x, z[5].x), pkrtz(z[6].x, z[7].x));
        zr[8] = (unsigned short)(__float_as_uint(z[8].x) >> 16);
        ((uint2*)(zr + 16))[0] = make_uint2(pkrtz(z[0].y, z[1].y), pkrtz(z[2].y, z[3].y));
        ((uint2*)(zr + 16))[1] = make_uint2(pkrtz(z[4].y, z[5].y), pkrtz(z[6].y, z[7].y));
        zr[24] = (unsigned short)(__float_as_uint(z[8].y) >> 16);
    };

    // ================ MFMA: wave wv owns px [32wv, 32wv+32) ================
    f32x4 acc[4][2];
#pragma unroll
    for (int m = 0; m < 4; ++m)
#pragma unroll
        for (int t = 0; t < 2; ++t) acc[m][t] = (f32x4){0.f, 0.f, 0.f, 0.f};

    auto mfma_step = [&](int j) {
        const int zp = j & 1;
        bf16x8 af[4];
        const unsigned short* wp = wsW + j * 2048 + a16 * 32 + kseg;
#pragma unroll
        for (int m = 0; m < 4; ++m)
            af[m] = *(const bf16x8*)(wp + m * 512);
        union { uint2 q2[2]; bf16x8 v; } bfr;
#pragma unroll
        for (int t = 0; t < 2; ++t) {
            const unsigned short* zp2 = &zbuf[zp][wv * 32 + t * 16 + a16][kseg];
            bfr.q2[0] = *(const uint2*)zp2;
            bfr.q2[1] = *(const uint2*)(zp2 + 4);
#pragma unroll
            for (int m = 0; m < 4; ++m)
                acc[m][t] = __builtin_amdgcn_mfma_f32_16x16x32_bf16(af[m], bfr.v, acc[m][t], 0, 0, 0);
        }
    };

    // ---- prologue (staging on sub1, R9 parity pipeline) ----
    if (sub == 1) { cload(0); cwrite(0); }
    __syncthreads();
    if (sub == 1) { fine_build(0); cload(1); }
    __syncthreads();
    if (sub == 1) { cwrite(1); cload(2); }
    __syncthreads();

    f32x2 zA[9];
#pragma unroll 1
    for (int i = 0; i <= 32; ++i) {
        if (i >= 1) mfma_step(i - 1);
        if (i < 32) {
            if (sub == 0) {
                partialA(i & 1, zA);
            } else {
                partialB_store(i & 1);
                if (i <= 29) cwrite(i & 1);
                if (i <= 30) fine_build((i + 1) & 1);
                if (i <= 28) cload(i + 3);
            }
        }
        __syncthreads();            // pbuf + staging ready
        if (i < 32 && sub == 0) combine_store(i & 1, zA);
        __syncthreads();            // zbuf[i&1] ready; pbuf reusable
    }

    // ---- epilogue: instance-norm partials + store y ----
#pragma unroll
    for (int m = 0; m < 4; ++m) {
#pragma unroll
        for (int r4 = 0; r4 < 4; ++r4) {
            float s = 0.f, q = 0.f;
#pragma unroll
            for (int t = 0; t < 2; ++t) {
                float v = acc[m][t][r4];
                s += v; q = fmaf(v, v, q);
            }
#pragma unroll
            for (int msk = 1; msk < 16; msk <<= 1) {
                s += __shfl_xor(s, msk);
                q += __shfl_xor(q, msk);
            }
            if (a16 == 0) {
                int o = m * 16 + (l >> 4) * 4 + r4;
                red1[wv][o] = s;
                red2[wv][o] = q;
            }
        }
    }

    const size_t nbase = (size_t)n * COUT * (H2 * W2);
#pragma unroll
    for (int m = 0; m < 4; ++m)
#pragma unroll
        for (int t = 0; t < 2; ++t) {
            int Y = ty0 + wv * 2 + t;
            int X = tx0 + a16;
#pragma unroll
            for (int r4 = 0; r4 < 4; ++r4) {
                int o = m * 16 + (l >> 4) * 4 + r4;
                out[nbase + (size_t)o * (H2 * W2) + Y * W2 + X] = acc[m][t][r4];
            }
        }
    __syncthreads();
    if (tid < 64) {
        float S1 = 0.f, S2 = 0.f;
#pragma unroll
        for (int wq = 0; wq < 8; ++wq) { S1 += red1[wq][tid]; S2 += red2[wq][tid]; }
        ws[WS_P1 + (n * COUT + tid) * 256 + tile] = S1;
        ws[WS_P2 + (n * COUT + tid) * 256 + tile] = S2;
    }
}

// ---------------------------------------------------------------------------
// Stats: reduce 256 tile-partials per (n,c)
// ---------------------------------------------------------------------------
__global__ void stats_kernel(float* __restrict__ ws) {
    const int co  = blockIdx.x;
    const int tid = threadIdx.x;   // 256
    float s1 = ws[WS_P1 + co * 256 + tid];
    float s2 = ws[WS_P2 + co * 256 + tid];
#pragma unroll
    for (int m = 1; m < 64; m <<= 1) { s1 += __shfl_xor(s1, m); s2 += __shfl_xor(s2, m); }
    __shared__ float r1[4], r2[4];
    if ((tid & 63) == 0) { r1[tid >> 6] = s1; r2[tid >> 6] = s2; }
    __syncthreads();
    if (tid == 0) {
        float S1 = r1[0] + r1[1] + r1[2] + r1[3];
        float S2 = r2[0] + r2[1] + r2[2] + r2[3];
        const float inv = 1.f / 65536.f;
        float mu  = S1 * inv;
        float var = S2 * inv - mu * mu;
        ws[WS_MU + co]   = mu;
        ws[WS_RSTD + co] = 1.f / sqrtf(var + 1e-5f);
    }
}

// ---------------------------------------------------------------------------
// Normalize + LeakyReLU(0.2), in place on d_out
// ---------------------------------------------------------------------------
__global__ void norm_kernel(float* __restrict__ out, const float* __restrict__ ws) {
    const int total = NB * COUT * H2 * W2 / 4;
    for (int idx = blockIdx.x * blockDim.x + threadIdx.x; idx < total;
         idx += gridDim.x * blockDim.x) {
        int co = idx >> 14;
        float mu = ws[WS_MU + co];
        float rs = ws[WS_RSTD + co];
        float4 v = ((float4*)out)[idx];
        float* p = (float*)&v;
#pragma unroll
        for (int j = 0; j < 4; ++j) {
            float t = (p[j] - mu) * rs;
            p[j] = (t >= 0.f) ? t : 0.2f * t;
        }
        ((float4*)out)[idx] = v;
    }
}

extern "C" void kernel_launch(void* const* d_in, const int* in_sizes, int n_in,
                              void* d_out, int out_size, void* d_ws, size_t ws_size,
                              hipStream_t stream) {
    const float* img = (const float*)d_in[0];
    const float* wgt = (const float*)d_in[1];
    float* out = (float*)d_out;
    float* ws  = (float*)d_ws;

    setup_w<<<32, 256, 0, stream>>>(wgt, ws);
    conv_kernel<<<NB * 256, 512, 0, stream>>>(img, out, ws);
    stats_kernel<<<256, 256, 0, stream>>>(ws);
    norm_kernel<<<2048, 256, 0, stream>>>(out, ws);
}

// Round 16
// 153.061 us; speedup vs baseline: 2.8962x; 1.3968x over previous
//
#include <hip/hip_runtime.h>

#define NB 4
#define CIN 64
#define COUT 64
#define H 128
#define W 128
#define H2 256
#define W2 256
#define HSX 23            // halo row stride (f32x2 units)
#define ZS 36             // zbuf row stride (ushorts) = 72B

// ws layout (float units)
#define WS_W    0         // bf16 weights ushort[32][64][32] = 32768 floats
#define WS_P1   32768     // per-tile partial sums  [4*64][256]
#define WS_P2   98304     // per-tile partial sumsq [4*64][256]
#define WS_MU   163840
#define WS_RSTD 164096

// ---------------------------------------------------------------------------
// Compile-time DISCO basis (replicates the numpy double-precision computation)
// ---------------------------------------------------------------------------
constexpr double csqrt(double x) {
    double g = x > 1.0 ? x : 1.0;
    for (int i = 0; i < 64; ++i) g = 0.5 * (g + x / g);
    return g;
}
constexpr double catan_pos(double x) {
    double f = 1.0;
    for (int i = 0; i < 6; ++i) { x = x / (1.0 + csqrt(1.0 + x * x)); f *= 2.0; }
    double x2 = x * x, s = 0.0, term = x;
    for (int n = 0; n < 10; ++n) { s += term / (2 * n + 1) * ((n & 1) ? -1.0 : 1.0); term *= x2; }
    return f * s;
}
constexpr double catan2c(double y, double x) {
    const double PI = 3.141592653589793;
    if (x == 0.0 && y == 0.0) return 0.0;
    double ax = x < 0 ? -x : x, ay = y < 0 ? -y : y;
    double a = (ax >= ay) ? catan_pos(ay / ax) : (PI / 2.0 - catan_pos(ax / ay));
    if (x < 0) a = PI - a;
    return (y < 0) ? -a : a;
}

struct PsiTab { double v[81][9]; };
constexpr PsiTab compute_psi() {
    PsiTab P{};
    const double hy = 1.0 / 256.0;
    const double rcut = 0.015;
    const double dr = 0.0075;
    const double PI = 3.141592653589793;
    const double TWO_PI = 6.283185307179586;
    const double dphi = PI / 2.0;
    for (int ky = 0; ky < 9; ++ky)
        for (int kx = 0; kx < 9; ++kx) {
            double dy = (double)(ky - 4) * hy;
            double dx = (double)(kx - 4) * hy;
            double r = csqrt(dy * dy + dx * dx);
            double phi = catan2c(dy, dx);
            if (phi < 0.0) phi += TWO_PI;
            for (int k = 0; k < 9; ++k) {
                int ir = (k == 0) ? 0 : ((k - 1) / 4 + 1);
                double ctr = ir * dr;
                double ad = r > ctr ? r - ctr : ctr - r;
                double rv = (ad <= dr && r <= rcut) ? 1.0 - ad / dr : 0.0;
                double val;
                if (k == 0) val = rv;
                else {
                    int ip = (k - 1) % 4;
                    double da = phi - ip * dphi; if (da < 0) da = -da;
                    double d2 = TWO_PI - da; if (d2 < da) da = d2;
                    double pv = (da <= dphi) ? 1.0 - da / dphi : 0.0;
                    val = rv * pv;
                }
                P.v[ky * 9 + kx][k] = val * (hy * hy);
            }
        }
    return P;
}

struct TapTab {
    int nt;
    int off[48];          // dy*HSX + dx (f32x2 offset from thread base)
    float val[48][9];
    bool nz[48][9];
};
constexpr TapTab make_taps() {
    TapTab T{};
    PsiTab P = compute_psi();
    for (int ky = 0; ky < 9; ++ky)
        for (int kx = 0; kx < 9; ++kx) {
            int t = ky * 9 + kx;
            bool any = false;
            for (int k = 0; k < 9; ++k) if (P.v[t][k] != 0.0) any = true;
            if (!any) continue;
            int dy = ky - 4, dx = kx - 4;    // support guarantees |dy|,|dx| <= 3
            T.off[T.nt] = dy * HSX + dx;
            for (int k = 0; k < 9; ++k) {
                T.val[T.nt][k] = (float)P.v[t][k];
                T.nz[T.nt][k] = (P.v[t][k] != 0.0);
            }
            T.nt++;
        }
    return T;
}
constexpr TapTab TT = make_taps();
constexpr int NT = TT.nt;
static_assert(NT > 0 && NT <= 48, "tap table overflow");

using f32x2  = __attribute__((ext_vector_type(2))) float;
using f32x4  = __attribute__((ext_vector_type(4))) float;
using bf16x8 = __attribute__((ext_vector_type(8))) short;

__device__ __forceinline__ unsigned short f2bf_rne(float f) {
    unsigned u = __float_as_uint(f);
    unsigned r = (u + 0x7fff + ((u >> 16) & 1)) >> 16;
    return (unsigned short)r;
}
// RTZ pack of two floats to one u32 of 2 bf16 (bias cancels in InstanceNorm)
__device__ __forceinline__ unsigned pkrtz(float a, float b) {
    return (__float_as_uint(a) >> 16) | (__float_as_uint(b) & 0xffff0000u);
}

// ---------------------------------------------------------------------------
// Setup: pre-transpose weights to bf16 wsW[g][o][32]  (kk = ch*16 + k, pads 0)
// ---------------------------------------------------------------------------
__global__ void setup_w(const float* __restrict__ wgt, float* __restrict__ ws) {
    unsigned short* wsW = (unsigned short*)(ws + WS_W);
    const int g = blockIdx.x;          // channel pair 0..31
    const int t = threadIdx.x;         // 256
    const int o = t >> 2;
    const int k0 = (t & 3) * 8;
#pragma unroll
    for (int j = 0; j < 8; ++j) {
        int kk = k0 + j;
        int ch = kk >> 4, k = kk & 15;
        float v = (k < 9) ? wgt[((size_t)o * CIN + 2 * g + ch) * 9 + k] : 0.f;
        wsW[g * 2048 + o * 32 + kk] = f2bf_rne(v);
    }
}

// ---------------------------------------------------------------------------
// Fused upsample + DISCO conv. Block = 16x16 px tile (256 px), 4 waves.
// 5-stage 1-barrier pipeline: cload(j)@j-3 -> cwrite(j)@j-2 -> fine_build(j)
// @j-1 -> zphase(j)@j -> MFMA(j)@j+1. coarse/halo/zbuf parity-double-buffered.
// ZS=36 (72B rows, b64 ops): LDS 50.7KB. Converged optimum of this structure:
// per-thread state ~160 regs (z18 + acc64AGPR + staging) -> 2 waves/SIMD;
// all occupancy-raising variants (R7/R10-R14) spilled or added LDS traffic.
// ---------------------------------------------------------------------------
__global__ __launch_bounds__(256, 2) void conv_kernel(const float* __restrict__ img,
                                                      float* __restrict__ out,
                                                      float* __restrict__ ws) {
    __shared__ __align__(16) unsigned short zbuf[2][256][ZS]; // [buf][px][kk]
    __shared__ f32x2 halo[2][22 * HSX];        // [buf] {ch0,ch1} f32
    __shared__ f32x2 coarse[2][14 * 15];       // [buf] {ch0,ch1} f32
    __shared__ float red1[4][64], red2[4][64];

    const int tid  = threadIdx.x;
    const int bid  = blockIdx.x;
    const int n    = bid >> 8;
    const int tile = bid & 255;
    const int ty0  = (tile >> 4) << 4;
    const int tx0  = (tile & 15) << 4;

    const int r = tid >> 4, c = tid & 15;
    const int hbase = (r + 3) * HSX + (c + 3);
    const int wv  = tid >> 6;
    const int l   = tid & 63;
    const int a16 = l & 15;
    const int kseg = (l >> 4) * 8;

    const unsigned short* wsW = (const unsigned short*)(ws + WS_W);

    // zero both zbuf buffers once (kk pads stay zero forever)
    {
        uint4* zr = (uint4*)&zbuf[0][0][0];
#pragma unroll
        for (int j = 0; j < 9; ++j) zr[tid + j * 256] = make_uint4(0, 0, 0, 0);
    }

    const float cs = 0.49803922f;   // 127/255

    // ---- block-constant coarse patch base ----
    int cy0 = (int)floorf((float)(ty0 - 3) * cs); cy0 = min(max(cy0, 0), 114);
    int cx0 = (int)floorf((float)(tx0 - 3) * cs); cx0 = min(max(cx0, 0), 114);

    // ---- coarse loader invariants (1 elem/thread, 196 used) ----
    const bool cok = tid < 196;
    const int ci = tid / 14, cj = tid - ci * 14;
    const int cgoff = (cy0 + ci) * W + (cx0 + cj);
    const int cwidx = ci * 15 + cj;
    float cv0 = 0.f, cv1 = 0.f;

    auto cload = [&](int g) {
        if (cok) {
            const float* b = img + ((size_t)n * CIN + 2 * g) * (H * W) + cgoff;
            cv0 = b[0];
            cv1 = b[H * W];
        }
    };
    auto cwrite = [&](int q) {
        if (cok) coarse[q][cwidx] = (f32x2){cv0, cv1};
    };

    // ---- fine-halo metadata: 484 elems, 2 slots, packed u32 + fy + fx ----
    unsigned fM[2];
    float fFY[2], fFX[2];
#pragma unroll
    for (int j = 0; j < 2; ++j) {
        int e = tid + j * 256;
        if (e < 484) {
            int hy = e / 22, hx = e - hy * 22;
            int uy = ty0 - 3 + hy, ux = tx0 - 3 + hx;
            unsigned zf = (((unsigned)uy >= 256u) || ((unsigned)ux >= 256u)) ? 1u : 0u;
            float syf = (float)uy * cs;
            float sxf = (float)ux * cs;
            int y0 = (int)floorf(syf);
            int x0 = (int)floorf(sxf);
            fFY[j] = syf - (float)y0;
            fFX[j] = sxf - (float)x0;
            int y0c = min(max(y0, 0), 127), x0c = min(max(x0, 0), 127);
            int dyo = min(y0c + 1, 127) - y0c;            // 0/1
            int dxo = min(x0c + 1, 127) - x0c;            // 0/1
            unsigned A = (unsigned)((y0c - cy0) * 15 + (x0c - cx0));
            fM[j] = A | ((unsigned)dxo << 9) | ((unsigned)dyo << 10) | (zf << 11)
                      | ((unsigned)(hy * HSX + hx) << 12);
        }
    }

    auto fine_build = [&](int q) {
#pragma unroll
        for (int j = 0; j < 2; ++j)
            if (tid < 484 - j * 256) {
                unsigned m = fM[j];
                const f32x2* cb = &coarse[q][0];
                int A = m & 511;
                int dxo = (m >> 9) & 1;
                int dyo = ((m >> 10) & 1) * 15;
                f32x2 c00 = cb[A],       c01 = cb[A + dxo];
                f32x2 c10 = cb[A + dyo], c11 = cb[A + dyo + dxo];
                f32x2 fyv = (f32x2){fFY[j], fFY[j]};
                f32x2 fxv = (f32x2){fFX[j], fFX[j]};
                f32x2 t0 = c00 + fyv * (c10 - c00);
                f32x2 t1 = c01 + fyv * (c11 - c01);
                f32x2 v  = t0 + fxv * (t1 - t0);
                if (m & (1u << 11)) v = (f32x2){0.f, 0.f};
                halo[q][m >> 12] = v;
            }
    };

    auto zphase = [&](int p) {
        const f32x2* hb = &halo[p][hbase - 72];   // all imm offsets >= 0
        f32x2 z[9];
#pragma unroll
        for (int k = 0; k < 9; ++k) z[k] = (f32x2){0.f, 0.f};
#pragma unroll
        for (int t = 0; t < NT; ++t) {
            f32x2 h = hb[72 + TT.off[t]];
#pragma unroll
            for (int k = 0; k < 9; ++k)
                if (TT.nz[t][k]) z[k] += h * TT.val[t][k];   // v_pk_fma_f32
        }
        unsigned short* zr = &zbuf[p][tid][0];
        ((uint2*)zr)[0] = make_uint2(pkrtz(z[0].x, z[1].x), pkrtz(z[2].x, z[3].x));
        ((uint2*)zr)[1] = make_uint2(pkrtz(z[4].x, z[5].x), pkrtz(z[6].x, z[7].x));
        zr[8] = (unsigned short)(__float_as_uint(z[8].x) >> 16);
        ((uint2*)(zr + 16))[0] = make_uint2(pkrtz(z[0].y, z[1].y), pkrtz(z[2].y, z[3].y));
        ((uint2*)(zr + 16))[1] = make_uint2(pkrtz(z[4].y, z[5].y), pkrtz(z[6].y, z[7].y));
        zr[24] = (unsigned short)(__float_as_uint(z[8].y) >> 16);
    };

    f32x4 acc[4][4];
#pragma unroll
    for (int m = 0; m < 4; ++m)
#pragma unroll
        for (int t = 0; t < 4; ++t) acc[m][t] = (f32x4){0.f, 0.f, 0.f, 0.f};

    // ---- prologue: coarse[0]=pair0, halo[0]=pair0, coarse[1]=pair1, regs=pair2
    cload(0); cwrite(0);
    __syncthreads();
    fine_build(0);        // coarse[0] -> halo[0]
    cload(1);
    __syncthreads();
    cwrite(1);            // regs(pair1) -> coarse[1]
    cload(2);
    __syncthreads();

#pragma unroll 1
    for (int i = 0; i <= 32; ++i) {
        // matrix pipe first: MFMA for pair i-1 (zbuf[(i-1)&1], weights i-1)
        if (i >= 1) {
            const int zp = (i - 1) & 1;
            bf16x8 af[4];
            const unsigned short* wp = wsW + (i - 1) * 2048 + a16 * 32 + kseg;
#pragma unroll
            for (int m = 0; m < 4; ++m)
                af[m] = *(const bf16x8*)(wp + m * 512);
            union { uint2 q2[2]; bf16x8 v; } bfr;
#pragma unroll
            for (int t = 0; t < 4; ++t) {
                const unsigned short* zp2 = &zbuf[zp][wv * 64 + t * 16 + a16][kseg];
                bfr.q2[0] = *(const uint2*)zp2;
                bfr.q2[1] = *(const uint2*)(zp2 + 4);
#pragma unroll
                for (int m = 0; m < 4; ++m)
                    acc[m][t] = __builtin_amdgcn_mfma_f32_16x16x32_bf16(af[m], bfr.v, acc[m][t], 0, 0, 0);
            }
        }
        if (i < 32)  zphase(i & 1);          // halo[i&1] -> zbuf[i&1]   (pair i)
        if (i <= 29) cwrite(i & 1);          // regs(pair i+2) -> coarse[i&1]
        if (i <= 30) fine_build((i + 1) & 1);// coarse[(i+1)&1] -> halo[(i+1)&1]
        if (i <= 28) cload(i + 3);           // global -> regs (pair i+3)
        __syncthreads();
    }

    // ---- epilogue: instance-norm partials + store y ----
#pragma unroll
    for (int m = 0; m < 4; ++m) {
#pragma unroll
        for (int r4 = 0; r4 < 4; ++r4) {
            float s = 0.f, q = 0.f;
#pragma unroll
            for (int t = 0; t < 4; ++t) {
                float v = acc[m][t][r4];
                s += v; q = fmaf(v, v, q);
            }
#pragma unroll
            for (int msk = 1; msk < 16; msk <<= 1) {
                s += __shfl_xor(s, msk);
                q += __shfl_xor(q, msk);
            }
            if (a16 == 0) {
                int o = m * 16 + (l >> 4) * 4 + r4;
                red1[wv][o] = s;
                red2[wv][o] = q;
            }
        }
    }

    const size_t nbase = (size_t)n * COUT * (H2 * W2);
#pragma unroll
    for (int m = 0; m < 4; ++m)
#pragma unroll
        for (int t = 0; t < 4; ++t) {
            int Y = ty0 + wv * 4 + t;
            int X = tx0 + a16;
#pragma unroll
            for (int r4 = 0; r4 < 4; ++r4) {
                int o = m * 16 + (l >> 4) * 4 + r4;
                out[nbase + (size_t)o * (H2 * W2) + Y * W2 + X] = acc[m][t][r4];
            }
        }
    __syncthreads();
    if (tid < 64) {
        float S1 = red1[0][tid] + red1[1][tid] + red1[2][tid] + red1[3][tid];
        float S2 = red2[0][tid] + red2[1][tid] + red2[2][tid] + red2[3][tid];
        ws[WS_P1 + (n * COUT + tid) * 256 + tile] = S1;
        ws[WS_P2 + (n * COUT + tid) * 256 + tile] = S2;
    }
}

// ---------------------------------------------------------------------------
// Stats: reduce 256 tile-partials per (n,c)
// ---------------------------------------------------------------------------
__global__ void stats_kernel(float* __restrict__ ws) {
    const int co  = blockIdx.x;
    const int tid = threadIdx.x;   // 256
    float s1 = ws[WS_P1 + co * 256 + tid];
    float s2 = ws[WS_P2 + co * 256 + tid];
#pragma unroll
    for (int m = 1; m < 64; m <<= 1) { s1 += __shfl_xor(s1, m); s2 += __shfl_xor(s2, m); }
    __shared__ float r1[4], r2[4];
    if ((tid & 63) == 0) { r1[tid >> 6] = s1; r2[tid >> 6] = s2; }
    __syncthreads();
    if (tid == 0) {
        float S1 = r1[0] + r1[1] + r1[2] + r1[3];
        float S2 = r2[0] + r2[1] + r2[2] + r2[3];
        const float inv = 1.f / 65536.f;
        float mu  = S1 * inv;
        float var = S2 * inv - mu * mu;
        ws[WS_MU + co]   = mu;
        ws[WS_RSTD + co] = 1.f / sqrtf(var + 1e-5f);
    }
}

// ---------------------------------------------------------------------------
// Normalize + LeakyReLU(0.2), in place on d_out
// ---------------------------------------------------------------------------
__global__ void norm_kernel(float* __restrict__ out, const float* __restrict__ ws) {
    const int total = NB * COUT * H2 * W2 / 4;
    for (int idx = blockIdx.x * blockDim.x + threadIdx.x; idx < total;
         idx += gridDim.x * blockDim.x) {
        int co = idx >> 14;
        float mu = ws[WS_MU + co];
        float rs = ws[WS_RSTD + co];
        float4 v = ((float4*)out)[idx];
        float* p = (float*)&v;
#pragma unroll
        for (int j = 0; j < 4; ++j) {
            float t = (p[j] - mu) * rs;
            p[j] = (t >= 0.f) ? t : 0.2f * t;
        }
        ((float4*)out)[idx] = v;
    }
}

extern "C" void kernel_launch(void* const* d_in, const int* in_sizes, int n_in,
                              void* d_out, int out_size, void* d_ws, size_t ws_size,
                              hipStream_t stream) {
    const float* img = (const float*)d_in[0];
    const float* wgt = (const float*)d_in[1];
    float* out = (float*)d_out;
    float* ws  = (float*)d_ws;

    setup_w<<<32, 256, 0, stream>>>(wgt, ws);
    conv_kernel<<<NB * 256, 256, 0, stream>>>(img, out, ws);
    stats_kernel<<<256, 256, 0, stream>>>(ws);
    norm_kernel<<<2048, 256, 0, stream>>>(out, ws);
}